// Round 1
// baseline (674.562 us; speedup 1.0000x reference)
//
#include <hip/hip_runtime.h>
#include <math.h>

// SwitchMOE: B=8,T=2048,D=1024,F=4096,E=16 ; capacity=1280, K=13
// Memory-bound: W1+W2 streaming = 536 MB dominates (~85us at 6.3 TB/s).
// Faithful reproduction of idx[::capacity] semantics incl. token-0
// fill-slot multiplicity (1 + K - n_kept(e0)).

#define TOKENS 16384
#define DD     1024
#define FF     4096
#define EE     16
#define CAP    1280
#define KMAX   13
#define NBLK   256   // router/keep blocks, 64 tokens each

// ---------------------------------------------------------------- router ----
// block = 256 thr (4 waves), 64 contiguous tokens per block.
// Each wave processes 4 tokens at a time: x in registers, Wr staged in LDS in
// 16KB chunks (j-loop), 64 accumulators, 6-level shfl_xor butterfly reduce.
__global__ __launch_bounds__(256) void router_kernel(
    const float* __restrict__ x, const float* __restrict__ Wr,
    int* __restrict__ top1, float* __restrict__ top1p,
    int* __restrict__ blockhist, float* __restrict__ p_sums)
{
    __shared__ float wrj[EE * 256];   // 16 KB: Wr[:, j*256:(j+1)*256]
    __shared__ float p_acc[EE];
    __shared__ int   hist[EE];

    const int tid  = threadIdx.x;
    const int wave = tid >> 6;
    const int lane = tid & 63;
    const int blk  = blockIdx.x;

    if (tid < EE) { p_acc[tid] = 0.0f; hist[tid] = 0; }

    for (int it = 0; it < 4; ++it) {
        const int tbase = blk * 64 + wave * 16 + it * 4;

        float4 xr[4][4];
        #pragma unroll
        for (int t = 0; t < 4; ++t) {
            const float4* xp = (const float4*)(x + (size_t)(tbase + t) * DD);
            #pragma unroll
            for (int j = 0; j < 4; ++j) xr[t][j] = xp[j * 64 + lane];
        }

        float acc[4][EE];
        #pragma unroll
        for (int t = 0; t < 4; ++t)
            #pragma unroll
            for (int e = 0; e < EE; ++e) acc[t][e] = 0.0f;

        for (int j = 0; j < 4; ++j) {
            __syncthreads();   // protect previous chunk readers
            #pragma unroll
            for (int k = 0; k < 4; ++k) {
                int i = tid + k * 256;            // float4 index in [0,1024)
                int e = i >> 6, c = i & 63;
                ((float4*)wrj)[i] = ((const float4*)Wr)[e * 256 + j * 64 + c];
            }
            __syncthreads();
            #pragma unroll
            for (int e = 0; e < EE; ++e) {
                float4 w = ((const float4*)(wrj + e * 256))[lane];
                #pragma unroll
                for (int t = 0; t < 4; ++t) {
                    acc[t][e] += xr[t][j].x * w.x + xr[t][j].y * w.y
                               + xr[t][j].z * w.z + xr[t][j].w * w.w;
                }
            }
        }

        // butterfly reduce: every lane ends with all 64 totals
        #pragma unroll
        for (int t = 0; t < 4; ++t)
            #pragma unroll
            for (int e = 0; e < EE; ++e) {
                float v = acc[t][e];
                v += __shfl_xor(v, 32);
                v += __shfl_xor(v, 16);
                v += __shfl_xor(v, 8);
                v += __shfl_xor(v, 4);
                v += __shfl_xor(v, 2);
                v += __shfl_xor(v, 1);
                acc[t][e] = v;
            }

        if (lane < 4) {
            // select this lane's token logits without dynamic reg indexing
            float lg[EE];
            #pragma unroll
            for (int e = 0; e < EE; ++e) {
                float v = acc[3][e];
                if (lane == 2) v = acc[2][e];
                if (lane == 1) v = acc[1][e];
                if (lane == 0) v = acc[0][e];
                lg[e] = v;
            }
            const int gt = tbase + lane;
            float mx = lg[0]; int bi = 0;
            #pragma unroll
            for (int e = 1; e < EE; ++e)
                if (lg[e] > mx) { mx = lg[e]; bi = e; }   // first-max like argmax
            float pr[EE];
            float s = 0.0f;
            #pragma unroll
            for (int e = 0; e < EE; ++e) { pr[e] = expf(lg[e] - mx); s += pr[e]; }
            const float inv = 1.0f / s;
            top1[gt]  = bi;
            top1p[gt] = inv;                 // = exp(0)/s = max prob
            #pragma unroll
            for (int e = 0; e < EE; ++e) atomicAdd(&p_acc[e], pr[e] * inv);
            atomicAdd(&hist[bi], 1);
        }
    }
    __syncthreads();
    if (tid < EE) {
        blockhist[blk * EE + tid] = hist[tid];
        atomicAdd(&p_sums[tid], p_acc[tid]);
    }
}

// ------------------------------------------------------------------ scan ----
// single block: exclusive prefix of blockhist over 256 blocks per expert,
// counts, n_kept, token-0 fill multiplicity, lb_loss.
__global__ __launch_bounds__(256) void scan_kernel(
    const int* __restrict__ blockhist, int* __restrict__ base,
    int* __restrict__ counts, int* __restrict__ nkept,
    const float* __restrict__ p_sums, const int* __restrict__ top1,
    float* __restrict__ mult0, float* __restrict__ lb_out)
{
    __shared__ int   hist_l[NBLK * EE];   // 16 KB
    __shared__ int   gsum[EE * 16];
    __shared__ float fp[EE];
    __shared__ int   nk_l[EE];

    const int tid = threadIdx.x;
    for (int i = tid; i < NBLK * EE; i += 256) hist_l[i] = blockhist[i];
    __syncthreads();

    const int e = tid >> 4, g = tid & 15;   // 16 experts x 16 groups of 16 blocks
    int s = 0;
    for (int b = g * 16; b < g * 16 + 16; ++b) s += hist_l[b * EE + e];
    gsum[e * 16 + g] = s;
    __syncthreads();

    int pre = 0;
    for (int g2 = 0; g2 < g; ++g2) pre += gsum[e * 16 + g2];
    int run = pre;
    for (int b = g * 16; b < g * 16 + 16; ++b) {
        base[b * EE + e] = run;
        run += hist_l[b * EE + e];
    }
    if (g == 15) {
        const int c = run;                      // total count for expert e
        counts[e] = c;
        const int nk = (c > 0) ? ((c - 1) / CAP + 1) : 0;
        nkept[e] = nk;
        nk_l[e]  = nk;
        fp[e] = ((float)c / (float)TOKENS) * (p_sums[e] / (float)TOKENS);
    }
    __syncthreads();
    if (tid == 0) {
        const int e0 = top1[0];
        mult0[0] = (float)(1 + KMAX - nk_l[e0]);  // token-0 fill multiplicity
        float sum = 0.0f;
        for (int i = 0; i < EE; ++i) sum += fp[i];
        lb_out[0] = (float)EE * sum * 0.01f;
    }
}

// ------------------------------------------------------------------ keep ----
// per 64-token block: within-block rank recount, kept-slot list + slot map.
__global__ __launch_bounds__(64) void keep_kernel(
    const int* __restrict__ top1, const float* __restrict__ top1p,
    const int* __restrict__ base, const float* __restrict__ mult0,
    int* __restrict__ kept_tok, float* __restrict__ kept_scale,
    int* __restrict__ slotmap)
{
    __shared__ int t1[64];
    const int tid = threadIdx.x;
    const int blk = blockIdx.x;
    const int gt  = blk * 64 + tid;
    const int e   = top1[gt];
    t1[tid] = e;
    __syncthreads();
    int r = 0;
    for (int i = 0; i < tid; ++i) r += (t1[i] == e) ? 1 : 0;
    const int rank = base[blk * EE + e] + r;
    if (rank % CAP == 0) {
        const int slot = rank / CAP;            // kth kept token has rank k*CAP
        kept_tok[e * KMAX + slot] = gt;
        float sc = top1p[gt];
        if (gt == 0) sc *= mult0[0];            // fold fill-slot multiplicity
        kept_scale[e * KMAX + slot] = sc;
        slotmap[gt] = e * KMAX + slot;
    }
}

// ------------------------------------------------------------------- E1 -----
// h[e][s][f] = gelu(W1[e,f,:] . x[t_s] + b1[e,f]). Wave per row, 4 rows/wave.
__global__ __launch_bounds__(256) void expert1_kernel(
    const float* __restrict__ x, const float* __restrict__ W1,
    const float* __restrict__ b1, const int* __restrict__ nkept,
    const int* __restrict__ kept_tok, float* __restrict__ h)
{
    const int e    = blockIdx.x >> 8;
    const int fblk = blockIdx.x & 255;
    const int ne   = nkept[e];
    if (ne == 0) return;
    const int wave = threadIdx.x >> 6;
    const int lane = threadIdx.x & 63;
    #pragma unroll
    for (int i = 0; i < 4; ++i) {
        const int f = fblk * 16 + wave * 4 + i;
        const float4* wrow = (const float4*)(W1 + ((size_t)e * FF + f) * DD);
        const float4 w0 = wrow[lane];
        const float4 w1 = wrow[64 + lane];
        const float4 w2 = wrow[128 + lane];
        const float4 w3 = wrow[192 + lane];
        for (int s = 0; s < ne; ++s) {
            const int t = kept_tok[e * KMAX + s];
            const float4* xp = (const float4*)(x + (size_t)t * DD);
            const float4 x0 = xp[lane];
            const float4 x1 = xp[64 + lane];
            const float4 x2 = xp[128 + lane];
            const float4 x3 = xp[192 + lane];
            float d = w0.x*x0.x + w0.y*x0.y + w0.z*x0.z + w0.w*x0.w
                    + w1.x*x1.x + w1.y*x1.y + w1.z*x1.z + w1.w*x1.w
                    + w2.x*x2.x + w2.y*x2.y + w2.z*x2.z + w2.w*x2.w
                    + w3.x*x3.x + w3.y*x3.y + w3.z*x3.z + w3.w*x3.w;
            d += __shfl_xor(d, 32);
            d += __shfl_xor(d, 16);
            d += __shfl_xor(d, 8);
            d += __shfl_xor(d, 4);
            d += __shfl_xor(d, 2);
            d += __shfl_xor(d, 1);
            if (lane == 0) {
                const float v = d + b1[e * FF + f];
                // exact gelu: 0.5*v*(1+erf(v/sqrt(2)))
                h[((size_t)e * KMAX + s) * FF + f] =
                    0.5f * v * (1.0f + erff(v * 0.70710678118654752440f));
            }
        }
    }
}

// ------------------------------------------------------------------- E2 -----
// eo[slot][d] = scale * (W2[e,d,:] . h[e][s][:] + b2[e,d]). Wave per row.
__global__ __launch_bounds__(256) void expert2_kernel(
    const float* __restrict__ h, const float* __restrict__ W2,
    const float* __restrict__ b2, const int* __restrict__ nkept,
    const float* __restrict__ kept_scale, float* __restrict__ eo)
{
    const int e    = blockIdx.x >> 6;
    const int dblk = blockIdx.x & 63;
    const int ne   = nkept[e];
    if (ne == 0) return;
    const int wave = threadIdx.x >> 6;
    const int lane = threadIdx.x & 63;
    #pragma unroll
    for (int i = 0; i < 4; ++i) {
        const int d = dblk * 16 + wave * 4 + i;
        const float4* wrow = (const float4*)(W2 + ((size_t)e * DD + d) * FF);
        float4 w[16];
        #pragma unroll
        for (int k = 0; k < 16; ++k) w[k] = wrow[k * 64 + lane];
        for (int s = 0; s < ne; ++s) {
            const float4* hp = (const float4*)(h + ((size_t)e * KMAX + s) * FF);
            float acc = 0.0f;
            #pragma unroll
            for (int k = 0; k < 16; ++k) {
                const float4 hv = hp[k * 64 + lane];
                acc += w[k].x*hv.x + w[k].y*hv.y + w[k].z*hv.z + w[k].w*hv.w;
            }
            acc += __shfl_xor(acc, 32);
            acc += __shfl_xor(acc, 16);
            acc += __shfl_xor(acc, 8);
            acc += __shfl_xor(acc, 4);
            acc += __shfl_xor(acc, 2);
            acc += __shfl_xor(acc, 1);
            if (lane == 0) {
                const float sc = kept_scale[e * KMAX + s];
                eo[((size_t)e * KMAX + s) * DD + d] = sc * (acc + b2[e * DD + d]);
            }
        }
    }
}

// ---------------------------------------------------------------- expand ----
// single coalesced pass writing the full output (zeros or scattered eo rows).
__global__ __launch_bounds__(256) void expand_kernel(
    const float* __restrict__ eo, const int* __restrict__ slotmap,
    float* __restrict__ out)
{
    const int nf4 = TOKENS * DD / 4;            // 4194304 float4
    int idx = blockIdx.x * 256 + threadIdx.x;
    const int stride = 4096 * 256;
    for (; idx < nf4; idx += stride) {
        const int t    = idx >> 8;              // 256 float4 per token
        const int slot = slotmap[t];
        float4 v = make_float4(0.0f, 0.0f, 0.0f, 0.0f);
        if (slot >= 0) v = ((const float4*)eo)[slot * 256 + (idx & 255)];
        ((float4*)out)[idx] = v;
    }
}

// -------------------------------------------------------------- launcher ----
extern "C" void kernel_launch(void* const* d_in, const int* in_sizes, int n_in,
                              void* d_out, int out_size, void* d_ws, size_t ws_size,
                              hipStream_t stream) {
    const float* x  = (const float*)d_in[0];
    const float* Wr = (const float*)d_in[1];
    const float* W1 = (const float*)d_in[2];
    const float* b1 = (const float*)d_in[3];
    const float* W2 = (const float*)d_in[4];
    const float* b2 = (const float*)d_in[5];
    float* out = (float*)d_out;

    char* p = (char*)d_ws;
    int*   top1       = (int*)p;    p += (size_t)TOKENS * 4;
    float* top1p      = (float*)p;  p += (size_t)TOKENS * 4;
    int*   slotmap    = (int*)p;    p += (size_t)TOKENS * 4;
    int*   blockhist  = (int*)p;    p += (size_t)NBLK * EE * 4;
    int*   base       = (int*)p;    p += (size_t)NBLK * EE * 4;
    int*   counts     = (int*)p;    p += (size_t)EE * 4;
    int*   nkept      = (int*)p;    p += (size_t)EE * 4;
    float* p_sums     = (float*)p;  p += (size_t)EE * 4;
    float* mult0      = (float*)p;  p += 16;
    int*   kept_tok   = (int*)p;    p += (size_t)EE * KMAX * 4;   // 832B, 16-mult
    float* kept_scale = (float*)p;  p += (size_t)EE * KMAX * 4;
    float* eo         = (float*)p;  p += (size_t)EE * KMAX * DD * 4;
    float* h          = (float*)p;  p += (size_t)EE * KMAX * FF * 4;
    (void)ws_size; (void)in_sizes; (void)n_in; (void)counts;

    hipMemsetAsync(p_sums, 0, EE * sizeof(float), stream);
    hipMemsetAsync(slotmap, 0xFF, (size_t)TOKENS * sizeof(int), stream);  // -1

    router_kernel<<<NBLK, 256, 0, stream>>>(x, Wr, top1, top1p, blockhist, p_sums);
    scan_kernel<<<1, 256, 0, stream>>>(blockhist, base, counts, nkept, p_sums,
                                       top1, mult0, out + (size_t)out_size - 1);
    keep_kernel<<<NBLK, 64, 0, stream>>>(top1, top1p, base, mult0,
                                         kept_tok, kept_scale, slotmap);
    expert1_kernel<<<EE * 256, 256, 0, stream>>>(x, W1, b1, nkept, kept_tok, h);
    expert2_kernel<<<EE * 64, 256, 0, stream>>>(h, W2, b2, nkept, kept_scale, eo);
    expand_kernel<<<4096, 256, 0, stream>>>(eo, slotmap, out);
}